// Round 9
// baseline (104.522 us; speedup 1.0000x reference)
//
#include <hip/hip_runtime.h>
#include <math.h>

#define B 32
#define C 256
#define HW 1024

typedef __attribute__((ext_vector_type(8))) short bf16x8;
typedef __attribute__((ext_vector_type(4))) float f32x4;

__device__ __forceinline__ unsigned short f2bf(float f) {
    unsigned int u = __float_as_uint(f);
    u += 0x7fffu + ((u >> 16) & 1u);  // RNE
    return (unsigned short)(u >> 16);
}

__device__ __forceinline__ void gload16(const void* g, void* l) {
    __builtin_amdgcn_global_load_lds(
        (const __attribute__((address_space(1))) unsigned int*)g,
        (__attribute__((address_space(3))) unsigned int*)l, 16, 0, 0);
}

// ---------------- Kernel 1: channel norms (fp32): norm and 1/norm ------------
__global__ __launch_bounds__(256) void norms_kernel(const float* __restrict__ x,
                                                    float* __restrict__ norm,
                                                    float* __restrict__ rnorm) {
    const int q = blockIdx.x * 256 + threadIdx.x;
    const int b = blockIdx.y;
    const float* xb = x + (size_t)b * C * HW + q;
    float s = 0.f;
#pragma unroll 8
    for (int c = 0; c < C; ++c) {
        float v = xb[(size_t)c * HW];
        s += v * v;
    }
    float n = fmaxf(sqrtf(s), 1e-8f);
    norm[b * HW + q] = n;
    rnorm[b * HW + q] = 1.f / n;
}

// ---------------- Kernel 2: cast W to bf16 ----------------
__global__ __launch_bounds__(256) void castw_kernel(const float* __restrict__ w,
                                                    unsigned short* __restrict__ wb) {
    int i = (blockIdx.x * 256 + threadIdx.x) * 4;
    float4 v = *(const float4*)(w + i);
    unsigned long long pk = (unsigned long long)f2bf(v.x) |
                            ((unsigned long long)f2bf(v.y) << 16) |
                            ((unsigned long long)f2bf(v.z) << 32) |
                            ((unsigned long long)f2bf(v.w) << 48);
    *(unsigned long long*)(wb + i) = pk;
}

// ---------------- Kernel 3: transpose + normalize + bf16 cast ----------------
__global__ __launch_bounds__(256) void prep_kernel(const float* __restrict__ x,
                                                   const float* __restrict__ rnorm,
                                                   unsigned short* __restrict__ xnT) {
    __shared__ float tile[64][65];
    const int t = threadIdx.x;
    const int q0 = blockIdx.x * 64, c0 = blockIdx.y * 64, b = blockIdx.z;
    const float* xb = x + ((size_t)b * C + c0) * HW + q0;
#pragma unroll
    for (int p = 0; p < 16; ++p) {
        int cc = p * 4 + (t >> 6);
        int qq = t & 63;
        tile[cc][qq] = xb[(size_t)cc * HW + qq];
    }
    __syncthreads();
    const float* rb = rnorm + b * HW + q0;
#pragma unroll
    for (int p = 0; p < 16; ++p) {
        int qq = p * 4 + (t >> 6);
        int cc = t & 63;
        float v = tile[cc][qq];
        float rn = rb[qq];
        xnT[((size_t)b * HW + q0 + qq) * C + c0 + cc] = f2bf(v * rn);
    }
}

// ---------------- Kernel 4: t = W*xn (*norm[k]) + bias ----------------
__global__ __launch_bounds__(256) void tgemm_kernel(
    const unsigned short* __restrict__ A, const unsigned short* __restrict__ Bm,
    unsigned short* __restrict__ Cb, const float* __restrict__ bias,
    const float* __restrict__ norm) {
    __shared__ unsigned short Asub[128 * 64];
    __shared__ unsigned short Bsub[128 * 64];
    const int t = threadIdx.x;
    const int bz = blockIdx.z;
    const int m0 = blockIdx.y * 128, n0 = blockIdx.x * 128;

    const int ug = ((t & 7) ^ ((t >> 3) & 7)) * 16;
    const char* gA = (const char*)A + (size_t)(m0 + (t >> 3)) * (C * 2) + ug;
    const char* gB = (const char*)(Bm + (size_t)bz * HW * C) +
                     (size_t)(n0 + (t >> 3)) * (C * 2) + ug;
    char* lA = (char*)Asub + t * 16;
    char* lB = (char*)Bsub + t * 16;
    const int rowStep = 32 * C * 2;

    const int lane = t & 63;
    const int wid = t >> 6;
    const int wr = wid >> 1, wc = wid & 1;
    const int lr = lane & 15, hi = lane >> 4;
    int rowA[4], rowB[4], sb[2];
#pragma unroll
    for (int i = 0; i < 4; ++i) rowA[i] = (wr * 64 + i * 16 + lr) * 128;
#pragma unroll
    for (int j = 0; j < 4; ++j) rowB[j] = (wc * 64 + j * 16 + lr) * 128;
#pragma unroll
    for (int kk = 0; kk < 2; ++kk) sb[kk] = ((hi + 4 * kk) ^ (lr & 7)) * 16;

    f32x4 acc[4][4];
#pragma unroll
    for (int i = 0; i < 4; ++i)
#pragma unroll
        for (int j = 0; j < 4; ++j) acc[i][j] = (f32x4)(0.f);

#pragma unroll
    for (int p = 0; p < 4; ++p) {
        gload16(gA + p * rowStep, lA + p * 4096);
        gload16(gB + p * rowStep, lB + p * 4096);
    }
    for (int ks = 0; ks < 4; ++ks) {
        __syncthreads();
#pragma unroll
        for (int kk = 0; kk < 2; ++kk) {
            bf16x8 av[4], bv[4];
#pragma unroll
            for (int i = 0; i < 4; ++i)
                av[i] = *(const bf16x8*)((const char*)Asub + rowA[i] + sb[kk]);
#pragma unroll
            for (int j = 0; j < 4; ++j)
                bv[j] = *(const bf16x8*)((const char*)Bsub + rowB[j] + sb[kk]);
#pragma unroll
            for (int i = 0; i < 4; ++i)
#pragma unroll
                for (int j = 0; j < 4; ++j)
                    acc[i][j] = __builtin_amdgcn_mfma_f32_16x16x32_bf16(
                        av[i], bv[j], acc[i][j], 0, 0, 0);
        }
        __syncthreads();
        if (ks + 1 < 4) {
            const char* gA2 = gA + (size_t)(ks + 1) * 128;
            const char* gB2 = gB + (size_t)(ks + 1) * 128;
#pragma unroll
            for (int p = 0; p < 4; ++p) {
                gload16(gA2 + p * rowStep, lA + p * 4096);
                gload16(gB2 + p * rowStep, lB + p * 4096);
            }
        }
    }
    const int mb = m0 + wr * 64 + hi * 4;
    const int nb = n0 + wc * 64 + lr;
    unsigned short* Cp = Cb + (size_t)bz * C * HW;
    float nrm[4];
#pragma unroll
    for (int j = 0; j < 4; ++j) nrm[j] = norm[bz * HW + nb + j * 16];
#pragma unroll
    for (int i = 0; i < 4; ++i)
#pragma unroll
        for (int r = 0; r < 4; ++r) {
            int m = mb + i * 16 + r;
            float bbv = bias[m];
#pragma unroll
            for (int j = 0; j < 4; ++j)
                Cp[(size_t)m * HW + nb + j * 16] = f2bf(acc[i][j][r] * nrm[j] + bbv);
        }
}

// ---------------- Kernel 5: fused flash sim+aggregate, counted-vmcnt pipeline
// Raw s_barrier + static vmcnt(N) (T3/T4): XK double-buffered, loads stay in
// flight across barriers; phase-B A-operand (t) loaded straight to VGPRs.
__global__ __launch_bounds__(512, 2) void fused_kernel(
    const unsigned short* __restrict__ xnT,  // [b][q][c] bf16
    const unsigned short* __restrict__ tb,   // [b][c][k] bf16
    float* __restrict__ out) {
    __shared__ unsigned short XQ[128 * 256];   // 64K resident, slot swz ^(q&15)
    __shared__ unsigned short XK0[128 * 64];   // 16K dbuf A, swz ^(k&7)
    __shared__ unsigned short XK1[128 * 64];   // 16K dbuf B
    __shared__ unsigned short SS[128 * 128];   // 32K [q][k], swz ^(q&15)
    const int t = threadIdx.x;
    const int b = blockIdx.y;
    const int qg0 = blockIdx.x * 128;
    const int lane = t & 63;
    const int wid = t >> 6;
    const int lr = lane & 15, hi = lane >> 4;

    const char* xq_g = (const char*)(xnT + ((size_t)b * HW + qg0) * C);
    const char* xk_gb = (const char*)(xnT + (size_t)b * HW * C);
    const char* t_gb = (const char*)(tb + (size_t)b * C * HW);

    const int qa = wid >> 1, ka = wid & 1;   // phase A wave roles
    const int cb4 = wid >> 1, qb = wid & 1;  // phase B wave roles

    // staging helper: 2 gload16 per thread -> one [128][64] chunk
    auto stage_xk = [&](int kg0, int cch, char* dst) {
#pragma unroll
        for (int p = 0; p < 2; ++p) {
            int u = p * 512 + t;
            int k = u >> 3, s = u & 7;
            int sp = s ^ (k & 7);
            gload16(xk_gb + (size_t)(kg0 + k) * 512 + cch * 128 + sp * 16,
                    dst + u * 16);
        }
    };

    f32x4 oacc[4][4];
#pragma unroll
    for (int i = 0; i < 4; ++i)
#pragma unroll
        for (int j = 0; j < 4; ++j) oacc[i][j] = (f32x4)(0.f);

    // ---- prologue: XQ resident + XK[kt0][cch0] -> buf0; one-time full drain
#pragma unroll
    for (int p = 0; p < 8; ++p) {
        int u = p * 512 + t;
        int q = u >> 5, s = u & 31;
        int sp = (s & 16) | ((s & 15) ^ (q & 15));
        gload16(xq_g + (size_t)q * 512 + sp * 16, (char*)XQ + (size_t)u * 16);
    }
    stage_xk(0, 0, (char*)XK0);
    asm volatile("s_waitcnt vmcnt(0)" ::: "memory");
    __builtin_amdgcn_s_barrier();

    for (int kt = 0; kt < 8; ++kt) {
        const int kg0 = kt * 128;
        f32x4 sacc[4][2];
#pragma unroll
        for (int i = 0; i < 4; ++i)
#pragma unroll
            for (int j = 0; j < 2; ++j) sacc[i][j] = (f32x4)(0.f);

        auto computeA = [&](const char* xk, int cch) {
#pragma unroll
            for (int cs = 0; cs < 2; ++cs) {
                bf16x8 av[4], bv[2];
#pragma unroll
                for (int i = 0; i < 4; ++i) {
                    int krow = ka * 64 + i * 16 + lr;
                    int off = (cs * 64 + hi * 16) ^ ((krow & 7) << 4);
                    av[i] = *(const bf16x8*)(xk + krow * 128 + off);
                }
#pragma unroll
                for (int j = 0; j < 2; ++j) {
                    int qrow = qa * 32 + j * 16 + lr;
                    int off = ((cch * 64 + cs * 32) * 2 + hi * 16) ^ ((qrow & 15) << 4);
                    bv[j] = *(const bf16x8*)((const char*)XQ + qrow * 512 + off);
                }
#pragma unroll
                for (int i = 0; i < 4; ++i)
#pragma unroll
                    for (int j = 0; j < 2; ++j)
                        sacc[i][j] = __builtin_amdgcn_mfma_f32_16x16x32_bf16(
                            av[i], bv[j], sacc[i][j], 0, 0, 0);
            }
        };

        bf16x8 tt[4][4];  // phase-B A-fragments, loaded global->VGPR mid-phase-A

        // cch0: compute buf0, prefetch cch1->buf1
        stage_xk(kg0, 1, (char*)XK1);
        asm volatile("s_waitcnt vmcnt(2)" ::: "memory");  // XK[0] landed
        __builtin_amdgcn_s_barrier();
        computeA((const char*)XK0, 0);
        __builtin_amdgcn_s_barrier();

        // cch1: compute buf1, prefetch cch2->buf0; issue TT register loads
        stage_xk(kg0, 2, (char*)XK0);
        asm volatile("s_waitcnt vmcnt(2)" ::: "memory");  // XK[1] landed
        __builtin_amdgcn_s_barrier();
        computeA((const char*)XK1, 1);
#pragma unroll
        for (int i = 0; i < 4; ++i)
#pragma unroll
            for (int kc = 0; kc < 4; ++kc)
                tt[i][kc] = *(const bf16x8*)(
                    t_gb + (size_t)(cb4 * 64 + i * 16 + lr) * 2048 +
                    (kg0 + kc * 32 + hi * 8) * 2);
        __builtin_amdgcn_s_barrier();

        // cch2: compute buf0, prefetch cch3->buf1
        stage_xk(kg0, 3, (char*)XK1);
        asm volatile("s_waitcnt vmcnt(18)" ::: "memory");  // XK[2] landed (TT16+XK3 in flight)
        __builtin_amdgcn_s_barrier();
        computeA((const char*)XK0, 2);
        __builtin_amdgcn_s_barrier();

        // cch3: compute buf1 (drain: XK[3] + TT all landed; TT needed next)
        asm volatile("s_waitcnt vmcnt(0)" ::: "memory");
        __builtin_amdgcn_s_barrier();
        computeA((const char*)XK1, 3);

        // relu^2 -> bf16 -> SS[q][k] (swizzled), then one sync before phase B
#pragma unroll
        for (int i = 0; i < 4; ++i)
#pragma unroll
            for (int j = 0; j < 2; ++j) {
                int q = qa * 32 + j * 16 + lr;
                int kb = ka * 64 + i * 16 + hi * 4;
                unsigned long long pk = 0;
#pragma unroll
                for (int r = 0; r < 4; ++r) {
                    float v = fmaxf(sacc[i][j][r], 0.f);
                    v = v * v;
                    pk |= (unsigned long long)f2bf(v) << (16 * r);
                }
                int off = (kb * 2) ^ ((q & 15) << 4);
                *(unsigned long long*)((char*)SS + q * 256 + off) = pk;
            }
        asm volatile("s_waitcnt lgkmcnt(0)" ::: "memory");
        __builtin_amdgcn_sched_barrier(0);
        __builtin_amdgcn_s_barrier();

        // phase B: oacc += tt (VGPR) x SS^T (LDS)
#pragma unroll
        for (int kc = 0; kc < 4; ++kc) {
            bf16x8 bv[4];
#pragma unroll
            for (int j = 0; j < 4; ++j) {
                int qrow = qb * 64 + j * 16 + lr;
                int off = (kc * 64 + hi * 16) ^ ((qrow & 15) << 4);
                bv[j] = *(const bf16x8*)((const char*)SS + qrow * 256 + off);
            }
#pragma unroll
            for (int i = 0; i < 4; ++i)
#pragma unroll
                for (int j = 0; j < 4; ++j)
                    oacc[i][j] = __builtin_amdgcn_mfma_f32_16x16x32_bf16(
                        tt[i][kc], bv[j], oacc[i][j], 0, 0, 0);
        }

        // prefetch next kt's cch0 -> buf0 (buf0 last read at cch2; all waves
        // are past the SS barrier, so no reader remains)
        if (kt < 7) stage_xk(kg0 + 128, 0, (char*)XK0);
    }

    // ---- epilogue: out[b][c][qg0 + q] fp32 ----
#pragma unroll
    for (int i = 0; i < 4; ++i)
#pragma unroll
        for (int r = 0; r < 4; ++r) {
            int c = cb4 * 64 + i * 16 + hi * 4 + r;
            float* op = out + ((size_t)b * C + c) * HW + qg0 + qb * 64 + lr;
#pragma unroll
            for (int j = 0; j < 4; ++j) op[j * 16] = oacc[i][j][r];
        }
}

extern "C" void kernel_launch(void* const* d_in, const int* in_sizes, int n_in,
                              void* d_out, int out_size, void* d_ws, size_t ws_size,
                              hipStream_t stream) {
    const float* x    = (const float*)d_in[0];  // (32,256,32,32)
    const float* w    = (const float*)d_in[1];  // (256,256)
    const float* bias = (const float*)d_in[2];  // (256,)
    float* out = (float*)d_out;

    char* ws = (char*)d_ws;
    float* norm         = (float*)ws;
    float* rnorm        = (float*)(ws + (128 << 10));
    unsigned short* wbf = (unsigned short*)(ws + (256 << 10));
    unsigned short* xnT = (unsigned short*)(ws + (384 << 10));
    unsigned short* tb  = (unsigned short*)(ws + (384 << 10) + (16u << 20));

    hipLaunchKernelGGL(norms_kernel, dim3(HW / 256, B), dim3(256), 0, stream,
                       x, norm, rnorm);
    hipLaunchKernelGGL(castw_kernel, dim3(C * C / 1024), dim3(256), 0, stream, w, wbf);
    hipLaunchKernelGGL(prep_kernel, dim3(HW / 64, C / 64, B), dim3(256), 0, stream,
                       x, rnorm, xnT);
    hipLaunchKernelGGL(tgemm_kernel, dim3(HW / 128, C / 128, B), dim3(256), 0, stream,
                       wbf, xnT, tb, bias, norm);
    hipLaunchKernelGGL(fused_kernel, dim3(HW / 128, B), dim3(512), 0, stream,
                       xnT, tb, out);
}

// Round 10
// 76.736 us; speedup vs baseline: 1.3621x; 1.3621x over previous
//
#include <hip/hip_runtime.h>
#include <math.h>

#define B 32
#define C 256
#define HW 1024

typedef __attribute__((ext_vector_type(8))) short bf16x8;
typedef __attribute__((ext_vector_type(4))) float f32x4;

__device__ __forceinline__ unsigned short f2bf(float f) {
    unsigned int u = __float_as_uint(f);
    u += 0x7fffu + ((u >> 16) & 1u);  // RNE
    return (unsigned short)(u >> 16);
}

__device__ __forceinline__ void gload16(const void* g, void* l) {
    __builtin_amdgcn_global_load_lds(
        (const __attribute__((address_space(1))) unsigned int*)g,
        (__attribute__((address_space(3))) unsigned int*)l, 16, 0, 0);
}

// ---- Kernel 1: fused norms + transpose + normalize + bf16 cast --------------
// Per block: x[b][0..256c][q0..q0+64] -> xnT[b][q][c] bf16, norm[b][q].
__global__ __launch_bounds__(256) void prepn_kernel(const float* __restrict__ x,
                                                    float* __restrict__ norm,
                                                    unsigned short* __restrict__ xnT) {
    __shared__ float xt[256][65];   // 66.6 KB (pad 65: conflict-free col reads)
    __shared__ float psum[4][64];
    __shared__ float rn[64];
    const int t = threadIdx.x;
    const int q0 = blockIdx.x * 64, b = blockIdx.y;
    const float* xb = x + (size_t)b * C * HW + q0;
#pragma unroll
    for (int p = 0; p < 16; ++p) {  // load 256x64 fp32 tile, float4 coalesced
        int u = p * 256 + t;
        int c = u >> 4, q4 = (u & 15) * 4;
        float4 v = *(const float4*)(xb + (size_t)c * HW + q4);
        xt[c][q4] = v.x; xt[c][q4 + 1] = v.y; xt[c][q4 + 2] = v.z; xt[c][q4 + 3] = v.w;
    }
    __syncthreads();
    {
        int cb = t >> 6, q = t & 63;
        float s = 0.f;
#pragma unroll
        for (int cc = 0; cc < 64; ++cc) {
            float v = xt[cb * 64 + cc][q];
            s += v * v;
        }
        psum[cb][q] = s;
    }
    __syncthreads();
    if (t < 64) {
        float s = psum[0][t] + psum[1][t] + psum[2][t] + psum[3][t];
        float n = fmaxf(sqrtf(s), 1e-8f);
        norm[b * HW + q0 + t] = n;
        rn[t] = 1.f / n;
    }
    __syncthreads();
    unsigned short* xrow = xnT + ((size_t)b * HW + q0) * C;
#pragma unroll
    for (int p = 0; p < 16; ++p) {  // transposed write: lane c-runs of 64
        int q = p * 4 + (t >> 6);
        float rnq = rn[q];
#pragma unroll
        for (int i = 0; i < 4; ++i) {
            int c = (t & 63) + 64 * i;   // lane-consecutive c: 128B segments
            xrow[(size_t)q * C + c] = f2bf(xt[c][q] * rnq);
        }
    }
}

// ---- Kernel 2: cast W to bf16 ----
__global__ __launch_bounds__(256) void castw_kernel(const float* __restrict__ w,
                                                    unsigned short* __restrict__ wb) {
    int i = (blockIdx.x * 256 + threadIdx.x) * 4;
    float4 v = *(const float4*)(w + i);
    unsigned long long pk = (unsigned long long)f2bf(v.x) |
                            ((unsigned long long)f2bf(v.y) << 16) |
                            ((unsigned long long)f2bf(v.z) << 32) |
                            ((unsigned long long)f2bf(v.w) << 48);
    *(unsigned long long*)(wb + i) = pk;
}

// ---- Kernel 3: t[b][o][k] = (sum_c W[o][c]*xn[b][k][c])*norm[k] + bias[o] ---
__global__ __launch_bounds__(256) void tgemm_kernel(
    const unsigned short* __restrict__ A, const unsigned short* __restrict__ Bm,
    unsigned short* __restrict__ Cb, const float* __restrict__ bias,
    const float* __restrict__ norm) {
    __shared__ unsigned short Asub[128 * 64];
    __shared__ unsigned short Bsub[128 * 64];
    const int t = threadIdx.x;
    const int bz = blockIdx.z;
    const int m0 = blockIdx.y * 128, n0 = blockIdx.x * 128;

    const int ug = ((t & 7) ^ ((t >> 3) & 7)) * 16;
    const char* gA = (const char*)A + (size_t)(m0 + (t >> 3)) * (C * 2) + ug;
    const char* gB = (const char*)(Bm + (size_t)bz * HW * C) +
                     (size_t)(n0 + (t >> 3)) * (C * 2) + ug;
    char* lA = (char*)Asub + t * 16;
    char* lB = (char*)Bsub + t * 16;
    const int rowStep = 32 * C * 2;

    const int lane = t & 63;
    const int wid = t >> 6;
    const int wr = wid >> 1, wc = wid & 1;
    const int lr = lane & 15, hi = lane >> 4;
    int rowA[4], rowB[4], sb[2];
#pragma unroll
    for (int i = 0; i < 4; ++i) rowA[i] = (wr * 64 + i * 16 + lr) * 128;
#pragma unroll
    for (int j = 0; j < 4; ++j) rowB[j] = (wc * 64 + j * 16 + lr) * 128;
#pragma unroll
    for (int kk = 0; kk < 2; ++kk) sb[kk] = ((hi + 4 * kk) ^ (lr & 7)) * 16;

    f32x4 acc[4][4];
#pragma unroll
    for (int i = 0; i < 4; ++i)
#pragma unroll
        for (int j = 0; j < 4; ++j) acc[i][j] = (f32x4)(0.f);

#pragma unroll
    for (int p = 0; p < 4; ++p) {
        gload16(gA + p * rowStep, lA + p * 4096);
        gload16(gB + p * rowStep, lB + p * 4096);
    }
    for (int ks = 0; ks < 4; ++ks) {
        __syncthreads();
#pragma unroll
        for (int kk = 0; kk < 2; ++kk) {
            bf16x8 av[4], bv[4];
#pragma unroll
            for (int i = 0; i < 4; ++i)
                av[i] = *(const bf16x8*)((const char*)Asub + rowA[i] + sb[kk]);
#pragma unroll
            for (int j = 0; j < 4; ++j)
                bv[j] = *(const bf16x8*)((const char*)Bsub + rowB[j] + sb[kk]);
#pragma unroll
            for (int i = 0; i < 4; ++i)
#pragma unroll
                for (int j = 0; j < 4; ++j)
                    acc[i][j] = __builtin_amdgcn_mfma_f32_16x16x32_bf16(
                        av[i], bv[j], acc[i][j], 0, 0, 0);
        }
        __syncthreads();
        if (ks + 1 < 4) {
            const char* gA2 = gA + (size_t)(ks + 1) * 128;
            const char* gB2 = gB + (size_t)(ks + 1) * 128;
#pragma unroll
            for (int p = 0; p < 4; ++p) {
                gload16(gA2 + p * rowStep, lA + p * 4096);
                gload16(gB2 + p * rowStep, lB + p * 4096);
            }
        }
    }
    const int mb = m0 + wr * 64 + hi * 4;
    const int nb = n0 + wc * 64 + lr;
    unsigned short* Cp = Cb + (size_t)bz * C * HW;
    float nrm[4];
#pragma unroll
    for (int j = 0; j < 4; ++j) nrm[j] = norm[bz * HW + nb + j * 16];
#pragma unroll
    for (int i = 0; i < 4; ++i)
#pragma unroll
        for (int r = 0; r < 4; ++r) {
            int m = mb + i * 16 + r;
            float bbv = bias[m];
#pragma unroll
            for (int j = 0; j < 4; ++j)
                Cp[(size_t)m * HW + nb + j * 16] = f2bf(acc[i][j][r] * nrm[j] + bbv);
        }
}

// ---- Kernel 4: fused flash sim+aggregate, QT=64, 2 blocks/CU, XCD swizzle ---
// LDS 80K exactly: XQ 32K + XK 16K + SS 16K + TT 16K -> 2 blocks/CU (4 w/SIMD).
__global__ __launch_bounds__(512, 4) void fused_kernel(
    const unsigned short* __restrict__ xnT,  // [b][q][c] bf16
    const unsigned short* __restrict__ tb,   // [b][c][k] bf16
    float* __restrict__ out) {
    __shared__ unsigned short XQ[64 * 256];   // [q][c], slot swz ^(q&15)
    __shared__ unsigned short XK[128 * 64];   // [k][c-chunk], swz ^(k&7)
    __shared__ unsigned short SS[64 * 128];   // [q][k], swz ^(q&15)
    __shared__ unsigned short TT[256 * 32];   // [c][32k-chunk], linear (64B rows)
    const int t = threadIdx.x;
    // XCD swizzle: all 16 q-tiles of a batch -> same XCD (L2 reuse of its
    // 2MB xnT + 2MB t streams). wgid%8 ~ XCD on MI355X round-robin dispatch.
    const int wgid = blockIdx.x;
    const int xcd = wgid & 7, g = wgid >> 3;
    const int qt = g & 15, bh = g >> 4;
    const int b = bh * 8 + xcd;
    const int qg0 = qt * 64;

    const int lane = t & 63;
    const int wid = t >> 6;
    const int lr = lane & 15, hi = lane >> 4;
    const int qh = wid & 1, kq = wid >> 1;  // A: q-half(32), k-quarter(32)
    const int cq = wid >> 1;                // B: c-quarter(64), q-half = qh

    const char* xq_g = (const char*)(xnT + ((size_t)b * HW + qg0) * C);
    const char* xk_gb = (const char*)(xnT + (size_t)b * HW * C);
    const char* t_gb = (const char*)(tb + (size_t)b * C * HW);

    // prologue: stage XQ [64][256] (source slot pre-swizzled, dest linear)
#pragma unroll
    for (int p = 0; p < 4; ++p) {
        int u = p * 512 + t;
        int q = u >> 5, s = u & 31;
        int sp = (s & 16) | ((s & 15) ^ (q & 15));
        gload16(xq_g + (size_t)q * 512 + sp * 16, (char*)XQ + (size_t)u * 16);
    }

    f32x4 oacc[4][2];
#pragma unroll
    for (int i = 0; i < 4; ++i)
#pragma unroll
        for (int j = 0; j < 2; ++j) oacc[i][j] = (f32x4)(0.f);

    for (int kt = 0; kt < 8; ++kt) {
        const int kg0 = kt * 128;
        f32x4 sacc[2][2];
#pragma unroll
        for (int i = 0; i < 2; ++i)
#pragma unroll
            for (int j = 0; j < 2; ++j) sacc[i][j] = (f32x4)(0.f);

        // ---- phase A: S'[128k][64q] over 4 c-chunks of 64 ----
        for (int cch = 0; cch < 4; ++cch) {
            __syncthreads();  // all readers of XK (and TT at cch==3) done
#pragma unroll
            for (int p = 0; p < 2; ++p) {  // stage XK [128][64]
                int u = p * 512 + t;
                int k = u >> 3, s = u & 7;
                int sp = s ^ (k & 7);
                gload16(xk_gb + (size_t)(kg0 + k) * 512 + cch * 128 + sp * 16,
                        (char*)XK + (size_t)u * 16);
            }
            if (cch == 3) {  // prestage TT chunk kc=0 (consumed after SS sync)
#pragma unroll
                for (int p = 0; p < 2; ++p) {
                    int u = p * 512 + t;
                    int c = u >> 2, s = u & 3;
                    gload16(t_gb + (size_t)c * 2048 + kg0 * 2 + s * 16,
                            (char*)TT + (size_t)u * 16);
                }
            }
            __syncthreads();  // staged data visible
#pragma unroll
            for (int cs = 0; cs < 2; ++cs) {
                bf16x8 av[2], bv[2];
#pragma unroll
                for (int i = 0; i < 2; ++i) {
                    int krow = kq * 32 + i * 16 + lr;
                    int off = (cs * 64 + hi * 16) ^ ((krow & 7) << 4);
                    av[i] = *(const bf16x8*)((const char*)XK + krow * 128 + off);
                }
#pragma unroll
                for (int j = 0; j < 2; ++j) {
                    int qrow = qh * 32 + j * 16 + lr;
                    int off = (cch * 128 + cs * 64 + hi * 16) ^ ((qrow & 15) << 4);
                    bv[j] = *(const bf16x8*)((const char*)XQ + qrow * 512 + off);
                }
#pragma unroll
                for (int i = 0; i < 2; ++i)
#pragma unroll
                    for (int j = 0; j < 2; ++j)
                        sacc[i][j] = __builtin_amdgcn_mfma_f32_16x16x32_bf16(
                            av[i], bv[j], sacc[i][j], 0, 0, 0);
            }
        }

        // ---- relu^2 -> bf16 -> SS[q][k] (b64 packed, swizzled) ----
#pragma unroll
        for (int i = 0; i < 2; ++i)
#pragma unroll
            for (int j = 0; j < 2; ++j) {
                int q = qh * 32 + j * 16 + lr;
                int kb = kq * 32 + i * 16 + hi * 4;
                unsigned long long pk = 0;
#pragma unroll
                for (int r = 0; r < 4; ++r) {
                    float v = fmaxf(sacc[i][j][r], 0.f);
                    v = v * v;
                    pk |= (unsigned long long)f2bf(v) << (16 * r);
                }
                int off = (kb * 2) ^ ((q & 15) << 4);
                *(unsigned long long*)((char*)SS + q * 256 + off) = pk;
            }
        __syncthreads();  // SS + TT0 ready

        // ---- phase B: out[256c][64q] += t[c][k] x S[q][k], 4 chunks of 32k --
#pragma unroll
        for (int kc = 0; kc < 4; ++kc) {
            if (kc > 0) {
                __syncthreads();  // prev TT chunk readers done
#pragma unroll
                for (int p = 0; p < 2; ++p) {
                    int u = p * 512 + t;
                    int c = u >> 2, s = u & 3;
                    gload16(t_gb + (size_t)c * 2048 + (kg0 + kc * 32) * 2 + s * 16,
                            (char*)TT + (size_t)u * 16);
                }
                __syncthreads();  // TT chunk ready
            }
            bf16x8 av[4], bv[2];
#pragma unroll
            for (int i = 0; i < 4; ++i) {
                int crow = cq * 64 + i * 16 + lr;
                av[i] = *(const bf16x8*)((const char*)TT + crow * 64 + hi * 16);
            }
#pragma unroll
            for (int j = 0; j < 2; ++j) {
                int qrow = qh * 32 + j * 16 + lr;
                int off = (kc * 64 + hi * 16) ^ ((qrow & 15) << 4);
                bv[j] = *(const bf16x8*)((const char*)SS + qrow * 256 + off);
            }
#pragma unroll
            for (int i = 0; i < 4; ++i)
#pragma unroll
                for (int j = 0; j < 2; ++j)
                    oacc[i][j] = __builtin_amdgcn_mfma_f32_16x16x32_bf16(
                        av[i], bv[j], oacc[i][j], 0, 0, 0);
        }
        // next kt's first XK stage is guarded by the cch0 top __syncthreads
    }

    // ---- epilogue: out[b][c][qg0 + q] fp32 ----
#pragma unroll
    for (int i = 0; i < 4; ++i)
#pragma unroll
        for (int r = 0; r < 4; ++r) {
            int c = cq * 64 + i * 16 + hi * 4 + r;
            float* op = out + ((size_t)b * C + c) * HW + qg0 + qh * 32 + lr;
#pragma unroll
            for (int j = 0; j < 2; ++j) op[j * 16] = oacc[i][j][r];
        }
}

extern "C" void kernel_launch(void* const* d_in, const int* in_sizes, int n_in,
                              void* d_out, int out_size, void* d_ws, size_t ws_size,
                              hipStream_t stream) {
    const float* x    = (const float*)d_in[0];  // (32,256,32,32)
    const float* w    = (const float*)d_in[1];  // (256,256)
    const float* bias = (const float*)d_in[2];  // (256,)
    float* out = (float*)d_out;

    // ws: norm 128K | wbf 128K | xnT 16M | t 16M
    char* ws = (char*)d_ws;
    float* norm         = (float*)ws;
    unsigned short* wbf = (unsigned short*)(ws + (128 << 10));
    unsigned short* xnT = (unsigned short*)(ws + (256 << 10));
    unsigned short* tb  = (unsigned short*)(ws + (256 << 10) + (16u << 20));

    hipLaunchKernelGGL(prepn_kernel, dim3(HW / 64, B), dim3(256), 0, stream,
                       x, norm, xnT);
    hipLaunchKernelGGL(castw_kernel, dim3(C * C / 1024), dim3(256), 0, stream, w, wbf);
    hipLaunchKernelGGL(tgemm_kernel, dim3(HW / 128, C / 128, B), dim3(256), 0, stream,
                       wbf, xnT, tb, bias, norm);
    hipLaunchKernelGGL(fused_kernel, dim3((HW / 64) * B), dim3(512), 0, stream,
                       xnT, tb, out);
}